// Round 5
// baseline (164.993 us; speedup 1.0000x reference)
//
#include <hip/hip_runtime.h>
#include <cstdint>
#include <cstddef>

// Problem constants
#define BQ 8
#define CDIM 64
#define HQ 64
#define WQ 64
#define KDIM 512
#define N_SIG 32768   // B*H*W
#define S_NNZ 4

// d_out float offsets (outputs concatenated flat in return order)
#define DIFF_ENC_OFF 2097152
#define DIFF_DICT_OFF 2097153
#define IDS_OFF 2097154
#define NUM_STEPS_OFF 18874370
#define MEAN_D_OFF 18874371
#define MEAN_Z_OFF 18874372
#define NORM_Z_OFF 18874373
#define TOP_PCT_OFF 18874374
#define NUM_ZEROS_OFF 18874375

// ws float-offsets
// words [0..3]  : accs[2] doubles: sumAbsZ, sumSq (zeroed by k_g block 0)
// words [4..8]  : hist[5] ints                    (zeroed by k_g block 0)
// [16..24)      : pd[8] per-diagonal-block |Dn| partial sums
#define WS_PD 16
#define WS_DNT 24
#define WS_G 32792
#define WS_WG 294936   // float4 per signal (deduped gamma)
#define WS_WI 426008   // int4 per signal (idx)

// Row-major normalized dictionary Dnr[c*512 + k] staged in d_out's ids region
// (written by k_g, consumed by k_fused, overwritten later by k_ei).
#define DNR_OFF 4194304

typedef float v2f __attribute__((ext_vector_type(2)));

// ---- Gram kernel: 64 blocks, G = Dn^T Dn (8x8 tiles of 64); diagonal blocks
// also emit DnT, Dnr and pd. alpha0 is never materialized in global memory.
__global__ __launch_bounds__(256) void k_g(const float* __restrict__ D,
                                           float* __restrict__ G,
                                           float* __restrict__ DnT,
                                           float* __restrict__ pd,
                                           float* __restrict__ Dnr,
                                           float* __restrict__ W) {
  __shared__ float Xs[64 * 64];
  __shared__ float Dns[64 * 64];
  __shared__ float partA[4][64];
  __shared__ float partB[4][64];
  __shared__ float invA[64];
  __shared__ float invB[64];
  int tid = threadIdx.x;
  int w = tid & 63, cq = tid >> 6;
  int ty = tid >> 4, tx = tid & 15;
  if (blockIdx.x == 0 && tid < 16) ((unsigned int*)W)[tid] = 0u;  // accs+hist zero

  int ti = (int)blockIdx.x >> 3, tj = (int)blockIdx.x & 7;
#pragma unroll
  for (int p = 0; p < 16; ++p) {
    int c = p * 4 + cq;
    Xs[c * 64 + w] = D[(size_t)c * KDIM + ti * 64 + w];
    Dns[c * 64 + w] = D[(size_t)c * KDIM + tj * 64 + w];
  }
  __syncthreads();
  float ssA = 0.f, ssB = 0.f;
#pragma unroll
  for (int cc = 0; cc < 16; ++cc) {
    int c = cq * 16 + cc;
    float a = Xs[c * 64 + w];
    ssA = fmaf(a, a, ssA);
    float bv = Dns[c * 64 + w];
    ssB = fmaf(bv, bv, ssB);
  }
  partA[cq][w] = ssA;
  partB[cq][w] = ssB;
  __syncthreads();
  if (tid < 64) {
    invA[tid] = 1.0f / sqrtf(partA[0][tid] + partA[1][tid] + partA[2][tid] + partA[3][tid]);
    invB[tid] = 1.0f / sqrtf(partB[0][tid] + partB[1][tid] + partB[2][tid] + partB[3][tid]);
  }
  __syncthreads();
  if (ti == tj) {
    // emit normalized DnT rows, Dnr slice, pd[ti] = sum|Dn| partial
    int kl = tid >> 2, cp = (tid & 3) * 16;
    float ia = invA[kl];
    int kg = ti * 64 + kl;              // global atom index
    float sabs = 0.f;
#pragma unroll
    for (int i = 0; i < 16; ++i) {
      int c = cp + i;
      float v = Xs[c * 64 + kl] * ia;
      DnT[(size_t)kg * CDIM + c] = v;
      Dnr[(size_t)c * KDIM + kg] = v;
      sabs += fabsf(v);
    }
#pragma unroll
    for (int off = 32; off >= 1; off >>= 1) sabs += __shfl_xor(sabs, off);
    __syncthreads();
    if ((tid & 63) == 0) partA[0][tid >> 6] = sabs;
    __syncthreads();
    if (tid == 0) pd[ti] = partA[0][0] + partA[0][1] + partA[0][2] + partA[0][3];
  }
  v2f acc[4][2] = {};
  for (int c = 0; c < 64; ++c) {
    float4 avv = *(const float4*)&Xs[c * 64 + ty * 4];
    float av[4] = {avv.x, avv.y, avv.z, avv.w};
    float4 bv = *(const float4*)&Dns[c * 64 + tx * 4];
    v2f b0 = {bv.x, bv.y}, b1 = {bv.z, bv.w};
#pragma unroll
    for (int i = 0; i < 4; ++i) {
      v2f a2 = {av[i], av[i]};
      acc[i][0] = __builtin_elementwise_fma(a2, b0, acc[i][0]);
      acc[i][1] = __builtin_elementwise_fma(a2, b1, acc[i][1]);
    }
  }
  float sn[4] = {invB[tx * 4], invB[tx * 4 + 1], invB[tx * 4 + 2], invB[tx * 4 + 3]};
#pragma unroll
  for (int i = 0; i < 4; ++i) {
    float im = invA[ty * 4 + i];
    float4 st = make_float4(acc[i][0].x * im * sn[0], acc[i][0].y * im * sn[1],
                            acc[i][1].x * im * sn[2], acc[i][1].y * im * sn[3]);
    *(float4*)&G[(size_t)(ti * 64 + ty * 4 + i) * KDIM + tj * 64 + tx * 4] = st;
  }
}

// ---- DPP wave-64 max of a non-negative float; returns wave-uniform (SGPR) value ----
__device__ __forceinline__ float wave_absmax_u(float m) {
#define DPP_MAX(ctrl)                                                              \
  {                                                                                \
    int t_ = __builtin_amdgcn_update_dpp(0, __float_as_int(m), (ctrl), 0xf, 0xf,   \
                                         true);                                    \
    m = fmaxf(m, __int_as_float(t_));                                              \
  }
  DPP_MAX(0x111) DPP_MAX(0x112) DPP_MAX(0x114) DPP_MAX(0x118)
  DPP_MAX(0x142) DPP_MAX(0x143)
#undef DPP_MAX
  return __int_as_float(__builtin_amdgcn_readlane(__float_as_int(m), 63));
}

// ---- fp32 solve, no pivoting (G_II near-identity), saved reciprocals ----
template <int SZ>
__device__ __forceinline__ void solve_sz(const float (&gs)[4][4], const float (&rhs)[4],
                                         float (&gamma)[4]) {
  float M[SZ][SZ];
  float y[SZ];
  float idg[SZ];
#pragma unroll
  for (int a = 0; a < SZ; ++a) {
    y[a] = rhs[a];
#pragma unroll
    for (int b = 0; b < SZ; ++b) M[a][b] = gs[a][b] + (a == b ? 1e-7f : 0.0f);
  }
#pragma unroll
  for (int p = 0; p < SZ; ++p) {
    float ip = __builtin_amdgcn_rcpf(M[p][p]);
    idg[p] = ip;
#pragma unroll
    for (int r = p + 1; r < SZ; ++r) {
      float f = M[r][p] * ip;
#pragma unroll
      for (int c = p + 1; c < SZ; ++c) M[r][c] = fmaf(-f, M[p][c], M[r][c]);
      y[r] = fmaf(-f, y[p], y[r]);
    }
  }
#pragma unroll
  for (int r = SZ - 1; r >= 0; --r) {
    float t = y[r];
#pragma unroll
    for (int c = r + 1; c < SZ; ++c) t = fmaf(-M[r][c], gamma[c], t);
    gamma[r] = t * idg[r];
  }
}

// ---- one OMP step for TWO independent signals (A,B), 2-way interleaved so
// B's argmax/loads fill A's L2 load-latency shadow and vice versa.
// Per-signal math identical to the sequential version (independent states).
template <int K>
__device__ __forceinline__ void omp_step_pair(
    int lane, const float* __restrict__ G, const float* asA, const float* asB,
    float (&alA)[8], float (&alB)[8], float (&GrA)[3][8], float (&GrB)[3][8],
    float (&gsA)[4][4], float (&gsB)[4][4], float (&rhA)[4], float (&rhB)[4],
    int (&ixA)[4], int (&ixB)[4], float (&gmA)[4], float (&gmB)[4]) {
  // per-lane argmax with lowest-m tie-break (strict >), both signals
  float mxA0 = fabsf(alA[0]);
  int miA = 0;
  float mxB0 = fabsf(alB[0]);
  int miB = 0;
#pragma unroll
  for (int m = 1; m < 8; ++m) {
    float vA = fabsf(alA[m]);
    miA = (vA > mxA0) ? m : miA;
    mxA0 = fmaxf(vA, mxA0);
    float vB = fabsf(alB[m]);
    miB = (vB > mxB0) ? m : miB;
    mxB0 = fmaxf(vB, mxB0);
  }
  float mxA = wave_absmax_u(mxA0);
  float mxB = wave_absmax_u(mxB0);
  unsigned long long bmA = __ballot(mxA0 == mxA);
  unsigned long long bmB = __ballot(mxB0 == mxB);
  int wlA = (int)__builtin_ctzll(bmA);
  int wlB = (int)__builtin_ctzll(bmB);
  int mwA = __builtin_amdgcn_readlane(miA, wlA);
  int mwB = __builtin_amdgcn_readlane(miB, wlB);
  int skA = wlA * 8 + mwA;  // wave-uniform
  int skB = wlB * 8 + mwB;
  ixA[K] = skA;
  ixB[K] = skB;

  const float* gbA = G + (size_t)skA * KDIM;
  const float* gbB = (const float*)__builtin_assume_aligned(G + (size_t)skB * KDIM, 16);
  // issue both G-row vector loads + both a0 LDS reloads up front
  float4 rA0, rA1, rB0, rB1, pA0, pA1, pB0, pB1;
  if constexpr (K < 3) {
    const float4* gpA = (const float4*)(gbA + lane * 8);
    const float4* gpB = (const float4*)(gbB + lane * 8);
    rA0 = gpA[0]; rA1 = gpA[1];
    rB0 = gpB[0]; rB1 = gpB[1];
    pA0 = *(const float4*)&asA[lane * 8];
    pA1 = *(const float4*)&asA[lane * 8 + 4];
    pB0 = *(const float4*)&asB[lane * 8];
    pB1 = *(const float4*)&asB[lane * 8 + 4];
    GrA[K][0] = rA0.x; GrA[K][1] = rA0.y; GrA[K][2] = rA0.z; GrA[K][3] = rA0.w;
    GrA[K][4] = rA1.x; GrA[K][5] = rA1.y; GrA[K][6] = rA1.z; GrA[K][7] = rA1.w;
    GrB[K][0] = rB0.x; GrB[K][1] = rB0.y; GrB[K][2] = rB0.z; GrB[K][3] = rB0.w;
    GrB[K][4] = rB1.x; GrB[K][5] = rB1.y; GrB[K][6] = rB1.z; GrB[K][7] = rB1.w;
  }

  // gs gathers (wave-uniform scalar loads) for both signals
#pragma unroll
  for (int b2 = 0; b2 < K; ++b2) {
    float vA = gbA[ixA[b2]];
    gsA[K][b2] = vA;
    gsA[b2][K] = vA;
    float vB = gbB[ixB[b2]];
    gsB[K][b2] = vB;
    gsB[b2][K] = vB;
  }
  gsA[K][K] = gbA[skA];
  gsB[K][K] = gbB[skB];
  rhA[K] = asA[skA];  // wave-uniform LDS scalar (parked alpha0)
  rhB[K] = asB[skB];

  solve_sz<K + 1>(gsA, rhA, gmA);
  solve_sz<K + 1>(gsB, rhB, gmB);

  if constexpr (K < 3) {
    float aA[8] = {pA0.x, pA0.y, pA0.z, pA0.w, pA1.x, pA1.y, pA1.z, pA1.w};
    float aB[8] = {pB0.x, pB0.y, pB0.z, pB0.w, pB1.x, pB1.y, pB1.z, pB1.w};
#pragma unroll
    for (int m = 0; m < 8; ++m) {
      float tA = aA[m];
      float tB = aB[m];
#pragma unroll
      for (int a = 0; a <= K; ++a) {
        tA = fmaf(-gmA[a], GrA[a][m], tA);
        tB = fmaf(-gmB[a], GrB[a][m], tB);
      }
      alA[m] = tA;
      alB[m] = tB;
    }
  }
}

// ---- fused alpha0 + OMP: 2048 blocks x 4 waves; 16 signals per block.
// GEMM: wave w computes atoms [w*128, w*128+128) for ALL 16 block-signals
// (acc = 16 v2f), D streamed from L2 (32 KB/wave), X read via uniform-address
// float4 loads (SMEM/L1 broadcast, zero LDS-port cost). Alpha parked in LDS
// (32 KB -> 5 blocks/CU), barrier, then each wave OMPs 4 signals as two
// 2-way-interleaved pairs (ILP across the per-step L2 latency chain).
__global__ __launch_bounds__(256, 4) void k_fused(const float* __restrict__ X,
                                                  const float* __restrict__ Dnr,
                                                  const float* __restrict__ G,
                                                  float4* __restrict__ wg,
                                                  int4* __restrict__ wi) {
  __shared__ __align__(16) float AS[16 * 512];  // alpha park: 16 signals (32 KB)
  int tid = threadIdx.x;
  int lane = tid & 63;
  int wv = __builtin_amdgcn_readfirstlane(tid >> 6);
  int bid = (int)blockIdx.x;
  int bh = bid >> 2, w0 = (bid & 3) * 16;  // bh = b*64+h
  int b = bh >> 6, h = bh & 63;

  // ---- GEMM: acc[sig] over this wave's 128-atom slice ----
  v2f acc[16] = {};
  const v2f* dp = (const v2f*)Dnr + wv * 64 + lane;  // + c*256 per row
  const float* xbase = X + ((size_t)b * CDIM * HQ + h) * WQ + w0;
#pragma unroll 4
  for (int c = 0; c < 64; ++c) {
    v2f d = dp[c * 256];                                   // 8B/lane, 512B/wave contig
    const float4* xp = (const float4*)(xbase + (size_t)c * (HQ * WQ));
    float4 x0 = xp[0], x1 = xp[1], x2 = xp[2], x3 = xp[3];  // uniform addr: bcast
    float xv[16] = {x0.x, x0.y, x0.z, x0.w, x1.x, x1.y, x1.z, x1.w,
                    x2.x, x2.y, x2.z, x2.w, x3.x, x3.y, x3.z, x3.w};
#pragma unroll
    for (int s = 0; s < 16; ++s) {
      v2f xx = {xv[s], xv[s]};
      acc[s] = __builtin_elementwise_fma(xx, d, acc[s]);
    }
  }

  // ---- park alpha: AS[sig][atom], this wave fills atoms wv*128..+128 ----
#pragma unroll
  for (int s = 0; s < 16; ++s)
    *(v2f*)&AS[s * 512 + wv * 128 + lane * 2] = acc[s];
  __syncthreads();

  // ---- OMP: wave wv handles block-signals wv*4..wv*4+4, as 2 pairs ----
#pragma unroll 1
  for (int sp = 0; sp < 2; ++sp) {
    int sbA = wv * 4 + sp * 2;
    int nA = bid * 16 + sbA;
    const float* asA = &AS[sbA * 512];
    const float* asB = &AS[(sbA + 1) * 512];
    float4 qa0 = *(const float4*)&asA[lane * 8];
    float4 qa1 = *(const float4*)&asA[lane * 8 + 4];
    float4 qb0 = *(const float4*)&asB[lane * 8];
    float4 qb1 = *(const float4*)&asB[lane * 8 + 4];
    float alA[8] = {qa0.x, qa0.y, qa0.z, qa0.w, qa1.x, qa1.y, qa1.z, qa1.w};
    float alB[8] = {qb0.x, qb0.y, qb0.z, qb0.w, qb1.x, qb1.y, qb1.z, qb1.w};
    float GrA[3][8], GrB[3][8];
    float gsA[4][4], gsB[4][4];
    float rhA[4], rhB[4];
    int ixA[4], ixB[4];
    float gmA[4], gmB[4];
    omp_step_pair<0>(lane, G, asA, asB, alA, alB, GrA, GrB, gsA, gsB, rhA, rhB,
                     ixA, ixB, gmA, gmB);
    omp_step_pair<1>(lane, G, asA, asB, alA, alB, GrA, GrB, gsA, gsB, rhA, rhB,
                     ixA, ixB, gmA, gmB);
    omp_step_pair<2>(lane, G, asA, asB, alA, alB, GrA, GrB, gsA, gsB, rhA, rhB,
                     ixA, ixB, gmA, gmB);
    omp_step_pair<3>(lane, G, asA, asB, alA, alB, GrA, GrB, gsA, gsB, rhA, rhB,
                     ixA, ixB, gmA, gmB);
    // dedupe: scatter-set semantics — later slot with same index wins
    bool a0k = (ixA[0] != ixA[1]) && (ixA[0] != ixA[2]) && (ixA[0] != ixA[3]);
    bool a1k = (ixA[1] != ixA[2]) && (ixA[1] != ixA[3]);
    bool a2k = (ixA[2] != ixA[3]);
    bool b0k = (ixB[0] != ixB[1]) && (ixB[0] != ixB[2]) && (ixB[0] != ixB[3]);
    bool b1k = (ixB[1] != ixB[2]) && (ixB[1] != ixB[3]);
    bool b2k = (ixB[2] != ixB[3]);
    if (lane == 0) {
      wg[nA] = make_float4(a0k ? gmA[0] : 0.f, a1k ? gmA[1] : 0.f,
                           a2k ? gmA[2] : 0.f, gmA[3]);
      wi[nA] = make_int4(ixA[0], ixA[1], ixA[2], ixA[3]);
      wg[nA + 1] = make_float4(b0k ? gmB[0] : 0.f, b1k ? gmB[1] : 0.f,
                               b2k ? gmB[2] : 0.f, gmB[3]);
      wi[nA + 1] = make_int4(ixB[0], ixB[1], ixB[2], ixB[3]);
    }
  }
}

// ---- fused epilogue: blocks 0..511 quant+stats, 512..2559 dense ids ----
__global__ __launch_bounds__(256) void k_ei(const float* __restrict__ X,
                                            const float* __restrict__ DnT,
                                            const float4* __restrict__ wg,
                                            const int4* __restrict__ wi,
                                            float* __restrict__ out,
                                            double* __restrict__ accs,
                                            int* __restrict__ hist) {
  __shared__ __align__(16) int sIdx[64][4];
  __shared__ __align__(16) float sKg[64][4];
  __shared__ float q[64 * 65];
  __shared__ float red[4];
  int tid = threadIdx.x;

  if (blockIdx.x < 512) {
    int bh = blockIdx.x;
    int b = bh >> 6, h = bh & 63;
    if (tid < 64) {
      int w = tid;
      int n = bh * 64 + w;
      int4 iv = wi[n];
      float4 gv = wg[n];  // already deduped in k_fused
      sIdx[w][0] = iv.x; sIdx[w][1] = iv.y; sIdx[w][2] = iv.z; sIdx[w][3] = iv.w;
      sKg[w][0] = gv.x; sKg[w][1] = gv.y; sKg[w][2] = gv.z; sKg[w][3] = gv.w;
      int nz = (int)(gv.x != 0.f) + (int)(gv.y != 0.f) +
               (int)(gv.z != 0.f) + (int)(gv.w != 0.f);
      float s = fabsf(gv.x) + fabsf(gv.y) + fabsf(gv.z) + fabsf(gv.w);
#pragma unroll
      for (int off = 32; off >= 1; off >>= 1) s += __shfl_xor(s, off);
#pragma unroll
      for (int v = 0; v < 5; ++v) {
        unsigned long long m = __ballot(nz == v);
        if (tid == 0) {
          int c = (int)__popcll(m);
          if (c) atomicAdd(&hist[v], c);
        }
      }
      if (tid == 0) atomicAdd(&accs[0], (double)s);
    }
    __syncthreads();

    int w2 = tid & 63, p = tid >> 6, c0 = p * 16;
    float acc[16] = {};
#pragma unroll
    for (int s = 0; s < 4; ++s) {
      int ks = sIdx[w2][s];
      float g = sKg[w2][s];
      const float4* dp = (const float4*)(DnT + (size_t)ks * CDIM + c0);
#pragma unroll
      for (int i4 = 0; i4 < 4; ++i4) {
        float4 d = dp[i4];
        acc[i4 * 4 + 0] = fmaf(g, d.x, acc[i4 * 4 + 0]);
        acc[i4 * 4 + 1] = fmaf(g, d.y, acc[i4 * 4 + 1]);
        acc[i4 * 4 + 2] = fmaf(g, d.z, acc[i4 * 4 + 2]);
        acc[i4 * 4 + 3] = fmaf(g, d.w, acc[i4 * 4 + 3]);
      }
    }
#pragma unroll
    for (int i = 0; i < 16; ++i) q[(c0 + i) * 65 + w2] = acc[i];
    __syncthreads();

    float sumsq = 0.f;
#pragma unroll
    for (int pass = 0; pass < 16; ++pass) {
      int c = pass * 4 + p;
      float qv = q[c * 65 + w2];
      size_t off = (((size_t)b * CDIM + c) * HQ + h) * WQ + w2;
      float xv = X[off];
      float d = qv - xv;
      sumsq = fmaf(d, d, sumsq);
      out[off] = qv;
    }

#pragma unroll
    for (int off = 32; off >= 1; off >>= 1) sumsq += __shfl_xor(sumsq, off);
    if ((tid & 63) == 0) red[tid >> 6] = sumsq;
    __syncthreads();
    if (tid == 0) atomicAdd(&accs[1], (double)(red[0] + red[1] + red[2] + red[3]));
  } else {
    // ---------------- dense ids write (dwordx4, 4 signals/thread) ----------------
    int bid = blockIdx.x - 512;
    int bh = bid >> 2, kq = bid & 3;
    int b = bh >> 6, h = bh & 63;
    if (tid < 64) {
      int n = bh * 64 + tid;
      *(int4*)&sIdx[tid][0] = wi[n];
      *(float4*)&sKg[tid][0] = wg[n];
    }
    __syncthreads();
    int w4 = (tid & 15) * 4, kl = tid >> 4;
    int4 I0 = *(const int4*)&sIdx[w4][0];
    int4 I1 = *(const int4*)&sIdx[w4 + 1][0];
    int4 I2 = *(const int4*)&sIdx[w4 + 2][0];
    int4 I3 = *(const int4*)&sIdx[w4 + 3][0];
    float4 G0 = *(const float4*)&sKg[w4][0];
    float4 G1 = *(const float4*)&sKg[w4 + 1][0];
    float4 G2 = *(const float4*)&sKg[w4 + 2][0];
    float4 G3 = *(const float4*)&sKg[w4 + 3][0];
    float* ids = out + IDS_OFF;
    size_t base = (((size_t)b * KDIM + kq * 128 + kl) * HQ + h) * WQ + w4;
#pragma unroll
    for (int pass = 0; pass < 8; ++pass) {
      int k = kq * 128 + pass * 16 + kl;
      // reverse-order select chain = scatter last-wins semantics
      float4 v;
      v.x = (k == I0.w) ? G0.w : (k == I0.z) ? G0.z : (k == I0.y) ? G0.y : (k == I0.x) ? G0.x : 0.f;
      v.y = (k == I1.w) ? G1.w : (k == I1.z) ? G1.z : (k == I1.y) ? G1.y : (k == I1.x) ? G1.x : 0.f;
      v.z = (k == I2.w) ? G2.w : (k == I2.z) ? G2.z : (k == I2.y) ? G2.y : (k == I2.x) ? G2.x : 0.f;
      v.w = (k == I3.w) ? G3.w : (k == I3.z) ? G3.z : (k == I3.y) ? G3.y : (k == I3.x) ? G3.x : 0.f;
      *(float4*)&ids[base + (size_t)pass * 16 * 4096] = v;
    }
  }
}

// ---- finalize scalars (separate 1-block dispatch; stream order = no fence needed) ----
__global__ __launch_bounds__(64) void k_final(const double* __restrict__ accs,
                                              const int* __restrict__ hist,
                                              const float* __restrict__ pd,
                                              float* __restrict__ out) {
  if (threadIdx.x == 0) {
    float sumAbsD = 0.f;
#pragma unroll
    for (int i = 0; i < 8; ++i) sumAbsD += pd[i];
    double sumAbsZ = accs[0], sumSq = accs[1];
    float diff = (float)(sumSq / 2097152.0);
    out[DIFF_ENC_OFF] = diff;
    out[DIFF_DICT_OFF] = diff;
    out[NUM_STEPS_OFF] = 4.0f;
    out[MEAN_D_OFF] = sumAbsD / 32768.0f;
    out[MEAN_Z_OFF] = (float)(sumAbsZ / 16777216.0);
    int h0 = hist[0], h1 = hist[1], h2 = hist[2], h3 = hist[3], h4 = hist[4];
    out[NORM_Z_OFF] = (float)((double)(h1 + 2 * h2 + 3 * h3 + 4 * h4) / 32768.0);
    int cum = 0, res = 0;
    for (int v = 4; v >= 0; --v) {
      cum += hist[v];
      if (cum >= 327) { res = v; break; }
    }
    out[TOP_PCT_OFF] = (float)res;
    out[NUM_ZEROS_OFF] = (float)h0;
  }
}

extern "C" void kernel_launch(void* const* d_in, const int* in_sizes, int n_in,
                              void* d_out, int out_size, void* d_ws, size_t ws_size,
                              hipStream_t stream) {
  (void)in_sizes; (void)n_in; (void)out_size; (void)ws_size;
  const float* X = (const float*)d_in[0];    // [8,64,64,64]
  const float* D = (const float*)d_in[1];    // [64,512]
  float* out = (float*)d_out;
  float* W = (float*)d_ws;
  double* accs = (double*)d_ws;
  int* hist = (int*)W + 4;
  float* pd = W + WS_PD;
  float* DnT = W + WS_DNT;
  float* G = W + WS_G;
  float4* wgam = (float4*)(W + WS_WG);
  int4* widx = (int4*)(W + WS_WI);
  float* Dnr = out + DNR_OFF;  // staged in ids region; k_ei overwrites later

  hipLaunchKernelGGL(k_g, dim3(64), dim3(256), 0, stream, D, G, DnT, pd, Dnr, W);
  hipLaunchKernelGGL(k_fused, dim3(2048), dim3(256), 0, stream, X, Dnr, G, wgam, widx);
  hipLaunchKernelGGL(k_ei, dim3(2560), dim3(256), 0, stream, X, DnT, wgam, widx, out, accs, hist);
  hipLaunchKernelGGL(k_final, dim3(1), dim3(64), 0, stream, accs, hist, pd, out);
}